// Round 18
// baseline (476.448 us; speedup 1.0000x reference)
//
#include <hip/hip_runtime.h>
#include <hip/hip_bf16.h>
#include <cstdint>
#include <cstddef>

// QRNN encoder, 3 layers. T=512 B=64 E=300 H=800.
// Chunked (4 x 128 steps) fused GEMM+scan, 3-role pipeline per dispatch:
//   D(c) = { L1(c), L2(c-1), L0(c+1) }, double-buffered H0/H1.
// R18: Et LDS round-trip ELIMINATED. Two layout permutations make MFMA
// output directly scannable in registers:
//  (1) A rows bit-swapped (row i holds t with bits[5:4]<->[3:2] swapped,
//      an involution) -> each lane holds 16 contiguous ordered t per col.
//  (2) Weight cols grouped per 16-h block: z in one nt-frag, f in the
//      next, o in frags 4/5 -> one lane owns z,f,o of the same chain.
// Scan: phase1 composes affine (a,b) in-register (packed bf16 = same
// numerics class as old bf16 Et path); phase2 8-segment LDS combine;
// phase3 register rescan + h=sigmoid(o)*c store at bit-swapped row.
// Bias folded via constant-1 K-pad column. GEMM: BK=64, XOR-swizzled LDS
// staging (0 conflicts), XCD-aware swizzle, async global_load_lds.
// Workspace ~85 MB.

typedef __bf16 bf16_t;
typedef __bf16 bf16x8 __attribute__((ext_vector_type(8)));
typedef float f32x4 __attribute__((ext_vector_type(4)));

#define T_C 128
#define NCHUNK 4
#define BATCH 64
#define EMB 300
#define HID 800
#define LDH 832                 // h buffer leading dim (K-pad for BK=64)
#define MC (T_C * BATCH)        // 8192 rows per chunk
#define CAST_OPS (MC * 320 / 8) // 327680 bf16x8 ops per chunk cast

__device__ __forceinline__ float fast_sigmoid(float x) {
  return 1.0f / (1.0f + __expf(-x));
}
__device__ __forceinline__ float fast_tanh(float x) {
  return 2.0f / (1.0f + __expf(-2.0f * x)) - 1.0f;
}
__device__ __forceinline__ float b2f(uint32_t u) {
  union { uint32_t i; float f; } x;
  x.i = u << 16;
  return x.f;
}
__device__ __forceinline__ uint32_t f2u16(float v) {
  union { bf16_t h; uint16_t u; } x;
  x.h = (bf16_t)v;
  return (uint32_t)x.u;
}

// row permutation: swap bits [5:4] <-> [3:2] (involution)
__device__ __forceinline__ int rowperm(int i) {
  return (i & 0xC3) | ((i & 0x30) >> 2) | ((i & 0x0C) << 2);
}

// ---- cast body: sent [rows t*64+b][300] fp32 -> A0 chunk cc, b-major,
// row-permuted: dst row (in chunk) i holds t = rowperm(i&127); col 300 =
// 1.0 (bias column), 301..319 = 0. ----
__device__ __forceinline__ void cast_op(const float* __restrict__ X,
                                        bf16_t* __restrict__ Y, int cc,
                                        int id) {
  const int rr = id / 40, cb = id - rr * 40;  // dst row in chunk, col-blk(8)
  const int b = rr >> 7, tl = rowperm(rr & 127);
  const float* src = X + (size_t)((cc * 128 + tl) * 64 + b) * EMB + cb * 8;
  bf16x8 w;
  if (cb < 37) {
    const f32x4 v0 = *(const f32x4*)src;
    const f32x4 v1 = *(const f32x4*)(src + 4);
#pragma unroll
    for (int e = 0; e < 4; ++e) {
      w[e] = (bf16_t)v0[e];
      w[e + 4] = (bf16_t)v1[e];
    }
  } else {
#pragma unroll
    for (int e = 0; e < 8; ++e) {
      const int col = cb * 8 + e;
      float v = (col < EMB) ? src[e] : (col == EMB ? 1.0f : 0.0f);
      w[e] = (bf16_t)v;
    }
  }
  *(bf16x8*)&Y[((size_t)cc * MC + rr) * 320 + cb * 8] = w;
}

// ---- P0: weights -> transposed bf16 buffers (+ chunk-0 cast at z=3).
// Bias folded at k == K (multiplies the constant-1 A column).
// zfo (z=0,1): Wm[2496][Kpad]; row n: jt=n/192, u0=n%192, w=u0/96, u=u0%96;
//   u<64:  p=u>>5, g=(u>>4)&1, fr=u&15 -> h=64jt+32w+16p+fr, src=g*800+h
//   u>=64: q=u-64 -> h=64jt+32w+q, src=1600+h
// zf (z=2): Wzf[1664][Kpad]; row n: jt=n/128, u0=n%128, w=u0>>6, u=u0&63;
//   p=u>>5, g=(u>>4)&1, fr=u&15 -> h=64jt+32w+16p+fr, src=g*800+h ----
__global__ __launch_bounds__(256) void prep_all(
    const float* __restrict__ W0, const float* __restrict__ W1,
    const float* __restrict__ W2, const float* __restrict__ B0,
    const float* __restrict__ B1, const float* __restrict__ B2,
    bf16_t* __restrict__ M0, bf16_t* __restrict__ M1, bf16_t* __restrict__ Z2,
    const float* __restrict__ sent, bf16_t* __restrict__ A0) {
  const int z = blockIdx.z;
  if (z == 3) {  // A0 chunk-0 cast
    const int id = (blockIdx.y * gridDim.x + blockIdx.x) * 256 + threadIdx.x;
    if (id < CAST_OPS) cast_op(sent, A0, 0, id);
    return;
  }
  const float* W = z == 0 ? W0 : (z == 1 ? W1 : W2);
  const float* Bv = z == 0 ? B0 : (z == 1 ? B1 : B2);
  bf16_t* Wt = z == 0 ? M0 : (z == 1 ? M1 : Z2);
  const int K = z == 0 ? 300 : 800;
  const int Kpad = z == 0 ? 320 : 832;
  const int Npad = (z < 2) ? 2496 : 1664;
  const int i = blockIdx.x, j = blockIdx.y;
  if (i * 32 >= Npad || j * 32 >= Kpad) return;
  __shared__ float tile[32][33];
  const int tx = threadIdx.x & 31, ty = threadIdx.x >> 5;
#pragma unroll
  for (int r = 0; r < 32; r += 8) {
    const int k = j * 32 + ty + r;
    const int n = i * 32 + tx;
    int h, src;
    if (z < 2) {
      const int jt = n / 192, u0 = n - jt * 192;
      const int w = u0 / 96, u = u0 - w * 96;
      if (u < 64) {
        const int p = u >> 5, g = (u >> 4) & 1, fc = u & 15;
        h = jt * 64 + w * 32 + p * 16 + fc;
        src = g * 800 + h;
      } else {
        const int q = u - 64;
        h = jt * 64 + w * 32 + q;
        src = 1600 + h;
      }
    } else {
      const int jt = n >> 7, u0 = n & 127;
      const int w = u0 >> 6, u = u0 & 63;
      const int p = u >> 5, g = (u >> 4) & 1, fc = u & 15;
      h = jt * 64 + w * 32 + p * 16 + fc;
      src = g * 800 + h;
    }
    float v = 0.0f;
    if (h < 800) {
      if (k < K) v = W[(size_t)k * 2400 + src];
      else if (k == K) v = Bv[src];  // bias row (A pad col is 1.0)
    }
    tile[ty + r][tx] = v;
  }
  __syncthreads();
#pragma unroll
  for (int r = 0; r < 32; r += 8) {
    const int n = i * 32 + ty + r, k = j * 32 + tx;
    if (n < Npad && k < Kpad)
      Wt[(size_t)n * Kpad + k] = (bf16_t)tile[tx][ty + r];
  }
}

// ---- async 16B global->LDS (wave-uniform base + lane*16 layout) ----
__device__ __forceinline__ void stage16(const bf16_t* gp, bf16_t* lp) {
  __builtin_amdgcn_global_load_lds((__attribute__((address_space(1))) void*)gp,
                                   (__attribute__((address_space(3))) void*)lp,
                                   16, 0, 0);
}

// GEMM core: 128 x (32*NTF) tile of A@Wt^T, accumulators stay in registers.
// 2x2 waves; wave = 64 rows x (16*NTF) cols. XOR-swizzled staging,
// conflict-free ds_read_b128 fragment reads.
// Per-lane result view (with the A row-perm): acc[mt][nt][r] = G[t][col],
// t = wm*64 + fq*16 + (mt*4+r) (contiguous ordered per lane), col =
// wn*(16*NTF) + nt*16 + fr. Segment seg = wm*4+fq covers t in [16seg,16seg+16).
template <int NTF>
__device__ __forceinline__ void gemm_tile_regs(
    const bf16_t* __restrict__ A, const bf16_t* __restrict__ Bt,
    bf16_t* __restrict__ S, int K, int mBase, int nBase,
    f32x4 (&acc)[4][NTF]) {
  bf16_t* As = S;
  bf16_t* Bs = S + 8192;
  const int tid = threadIdx.x;
  const int wave = tid >> 6, lane = tid & 63;
  const int wm = wave >> 1, wn = wave & 1;
  const int srow = tid >> 3;
  const int scolSw = ((tid & 7) ^ (srow & 7)) * 8;
  const size_t aBase = (size_t)(mBase + srow) * K + scolSw;
  const size_t bBase = (size_t)(nBase + srow) * K + scolSw;
  const int ldsOff = tid * 8;

#pragma unroll
  for (int mt = 0; mt < 4; ++mt)
#pragma unroll
    for (int nt = 0; nt < NTF; ++nt) {
      f32x4 zz = {0.0f, 0.0f, 0.0f, 0.0f};
      acc[mt][nt] = zz;
    }

  const int fr = lane & 15, fq = lane >> 4;
  const int x0 = fr & 7;
  const int ckEl0 = (fq ^ x0) * 8;
  const int ckEl1 = ((4 + fq) ^ x0) * 8;

  for (int k0 = 0; k0 < K; k0 += 64) {
#pragma unroll
    for (int p = 0; p < 4; ++p)
      stage16(A + aBase + (size_t)(32 * p) * K + k0, &As[ldsOff + p * 2048]);
#pragma unroll
    for (int p = 0; p < NTF; ++p)
      stage16(Bt + bBase + (size_t)(32 * p) * K + k0, &Bs[ldsOff + p * 2048]);
    __syncthreads();
#pragma unroll
    for (int kh = 0; kh < 2; ++kh) {
      const int ck = kh ? ckEl1 : ckEl0;
      bf16x8 af[4], bfv[NTF];
#pragma unroll
      for (int mt = 0; mt < 4; ++mt)
        af[mt] = *(const bf16x8*)&As[(wm * 64 + mt * 16 + fr) * 64 + ck];
#pragma unroll
      for (int nt = 0; nt < NTF; ++nt)
        bfv[nt] = *(const bf16x8*)&Bs[(wn * (16 * NTF) + nt * 16 + fr) * 64 + ck];
#pragma unroll
      for (int mt = 0; mt < 4; ++mt)
#pragma unroll
        for (int nt = 0; nt < NTF; ++nt)
          acc[mt][nt] = __builtin_amdgcn_mfma_f32_16x16x32_bf16(
              af[mt], bfv[nt], acc[mt][nt], 0, 0, 0);
    }
    __syncthreads();
  }
}

// ---- role body: zfo-GEMM (192 cols) + in-register scan + h epilogue ----
// Chain p (0,1): z at nt 2p, f at nt 2p+1, o at nt 4+p; chain h =
// ntile*64 + wn*32 + p*16 + fr.
__device__ __forceinline__ void scan_h_body(
    const bf16_t* __restrict__ A, const bf16_t* __restrict__ Wm,
    bf16_t* __restrict__ Hout, float* __restrict__ carry,
    float* __restrict__ outC, int K, int outOff, int first, int last, int b,
    int ntile, bf16_t* S, float (*SA)[64], float (*SB)[64], float (*SC)[64]) {
  f32x4 acc[4][6];
  gemm_tile_regs<6>(A, Wm, S, K, b * 128, ntile * 192, acc);

  const int tid = threadIdx.x;
  const int wave = tid >> 6, lane = tid & 63;
  const int wm = wave >> 1, wn = wave & 1;
  const int fr = lane & 15, fq = lane >> 4;
  const int seg = wm * 4 + fq;

  // phase 1: activate from registers, pack (a,b) bf16, compose segment map
  uint32_t ab[2][16];
#pragma unroll
  for (int p = 0; p < 2; ++p) {
    float Aa = 1.0f, Bb = 0.0f;
#pragma unroll
    for (int mt = 0; mt < 4; ++mt)
#pragma unroll
      for (int r = 0; r < 4; ++r) {
        const int q = mt * 4 + r;
        const float zv = fast_tanh(acc[mt][2 * p][r]);
        const float fv = fast_sigmoid(acc[mt][2 * p + 1][r]);
        const uint32_t ua = f2u16(1.0f - fv), ub = f2u16(fv * zv);
        ab[p][q] = ua | (ub << 16);
        const float af = b2f(ua), bf_ = b2f(ub << 16 >> 16);
        Aa *= af;
        Bb = fmaf(af, Bb, b2f(ub));
      }
    const int cl = wn * 32 + p * 16 + fr;
    SA[seg][cl] = Aa;
    SB[seg][cl] = Bb;
  }
  __syncthreads();
  // phase 2: serial combine over 8 segments, one thread per chain
  if (tid < 64) {
    const int h2 = ntile * 64 + tid;
    const bool ok2 = (h2 < HID);
    float c = (first || !ok2) ? 0.0f : carry[b * HID + h2];
#pragma unroll
    for (int ss = 0; ss < 8; ++ss) {
      SC[ss][tid] = c;
      c = fmaf(SA[ss][tid], c, SB[ss][tid]);
    }
    if (ok2) {
      carry[b * HID + h2] = c;
      if (last) outC[b * 2400 + outOff + h2] = c;
    }
  }
  __syncthreads();
  // phase 3: register rescan; h = sigmoid(o') * c; store at bit-swapped row
#pragma unroll
  for (int p = 0; p < 2; ++p) {
    const int cl = wn * 32 + p * 16 + fr;
    const int h = ntile * 64 + cl;
    const bool hOK = (h < HID);
    const bf16_t padv = (h == HID) ? (bf16_t)1.0f : (bf16_t)0.0f;
    float c = SC[seg][cl];
#pragma unroll
    for (int mt = 0; mt < 4; ++mt)
#pragma unroll
      for (int r = 0; r < 4; ++r) {
        const int q = mt * 4 + r;
        c = fmaf(b2f(ab[p][q] & 0xffffu), c, b2f(ab[p][q] >> 16));
        const float o = fast_sigmoid(acc[mt][4 + p][r]);
        const int row = b * 128 + wm * 64 + mt * 16 + fq * 4 + r;
        Hout[(size_t)row * LDH + h] = hOK ? (bf16_t)(o * c) : padv;
      }
  }
}

// ---- role body: zf-only GEMM (128 cols) + scan; carry/out only ----
__device__ __forceinline__ void scan_c_body(
    const bf16_t* __restrict__ A, const bf16_t* __restrict__ Wzf,
    float* __restrict__ carry, float* __restrict__ outC, int K, int outOff,
    int first, int last, int b, int ntile, bf16_t* S, float (*SA)[64],
    float (*SB)[64]) {
  f32x4 acc[4][4];
  gemm_tile_regs<4>(A, Wzf, S, K, b * 128, ntile * 128, acc);

  const int tid = threadIdx.x;
  const int wave = tid >> 6, lane = tid & 63;
  const int wm = wave >> 1, wn = wave & 1;
  const int fr = lane & 15, fq = lane >> 4;
  const int seg = wm * 4 + fq;

#pragma unroll
  for (int p = 0; p < 2; ++p) {
    float Aa = 1.0f, Bb = 0.0f;
#pragma unroll
    for (int mt = 0; mt < 4; ++mt)
#pragma unroll
      for (int r = 0; r < 4; ++r) {
        const float zv = fast_tanh(acc[mt][2 * p][r]);
        const float fv = fast_sigmoid(acc[mt][2 * p + 1][r]);
        const float af = b2f(f2u16(1.0f - fv));
        const float bf_ = b2f(f2u16(fv * zv));
        Aa *= af;
        Bb = fmaf(af, Bb, bf_);
      }
    const int cl = wn * 32 + p * 16 + fr;
    SA[seg][cl] = Aa;
    SB[seg][cl] = Bb;
  }
  __syncthreads();
  if (tid < 64) {
    const int h2 = ntile * 64 + tid;
    const bool ok2 = (h2 < HID);
    float c = (first || !ok2) ? 0.0f : carry[b * HID + h2];
#pragma unroll
    for (int ss = 0; ss < 8; ++ss) c = fmaf(SA[ss][tid], c, SB[ss][tid]);
    if (ok2) {
      carry[b * HID + h2] = c;
      if (last) outC[b * 2400 + outOff + h2] = c;
    }
  }
}

__device__ __forceinline__ void block_tile(int& b, int& ntile) {
  const int nT = 13;
  const int L = blockIdx.y * nT + blockIdx.x;
  const int xcd = L & 7, j = L >> 3;
  b = xcd * 8 + j / nT;
  ntile = j % nT;
}

// ---- multi-role dispatch: blockIdx.z selects an independent role ----
struct Role {
  const bf16_t* A;  // type 3: fp32 src (reinterpreted)
  const bf16_t* W;
  bf16_t* Hout;     // type 1: h out; type 3: bf16 A0 base dst
  float* carry;
  int K;
  int outOff;       // type 3: chunk index
  int type;         // 1 = zfo+scan+h; 2 = zf+scan; 3 = A0 chunk cast
  int first;
  int last;
};

__global__ __launch_bounds__(256, 3) void gemm_scan_multi(
    Role r0, Role r1, Role r2, Role r3, float* __restrict__ outC) {
  __shared__ __align__(16) bf16_t S[20480];  // staging only (Et eliminated)
  __shared__ float SA[8][64], SB[8][64], SC[8][64];
  const Role r = blockIdx.z == 0
                     ? r0
                     : (blockIdx.z == 1 ? r1 : (blockIdx.z == 2 ? r2 : r3));
  if (r.type == 3) {
    int id = (blockIdx.y * gridDim.x + blockIdx.x) * 256 + threadIdx.x;
    const int stride = gridDim.x * gridDim.y * 256;  // 212992 at (13,64)
#pragma unroll
    for (int it = 0; it < 2; ++it, id += stride)
      if (id < CAST_OPS) cast_op((const float*)r.A, r.Hout, r.outOff, id);
    return;
  }
  int b, ntile;
  block_tile(b, ntile);
  if (r.type == 1)
    scan_h_body(r.A, r.W, r.Hout, r.carry, outC, r.K, r.outOff, r.first,
                r.last, b, ntile, S, SA, SB, SC);
  else
    scan_c_body(r.A, r.W, r.carry, outC, r.K, r.outOff, r.first, r.last, b,
                ntile, S, SA, SB);
}

// Dedicated final-L2 kernel: ~36 KB LDS -> 4 blocks/CU, no block-wave tail.
__global__ __launch_bounds__(256, 4) void gemm_scan_c4(
    const bf16_t* __restrict__ A, const bf16_t* __restrict__ Wzf,
    float* __restrict__ carry, float* __restrict__ outC, int K, int outOff,
    int first, int last) {
  __shared__ __align__(16) bf16_t S[16384];
  __shared__ float SA[8][64], SB[8][64];
  int b, ntile;
  block_tile(b, ntile);
  scan_c_body(A, Wzf, carry, outC, K, outOff, first, last, b, ntile, S, SA,
              SB);
}

extern "C" void kernel_launch(void* const* d_in, const int* in_sizes, int n_in,
                              void* d_out, int out_size, void* d_ws, size_t ws_size,
                              hipStream_t stream) {
  const float* sent = (const float*)d_in[0];
  // d_in[1] = lengths: unused by the reference
  const float* W0 = (const float*)d_in[2];
  const float* b0 = (const float*)d_in[3];
  const float* W1 = (const float*)d_in[4];
  const float* b1 = (const float*)d_in[5];
  const float* W2 = (const float*)d_in[6];
  const float* b2 = (const float*)d_in[7];
  float* out = (float*)d_out;

  char* ws = (char*)d_ws;
  size_t off = 0;
  auto alloc = [&](size_t bytes) {
    void* p = ws + off;
    off += (bytes + 255) & ~(size_t)255;
    return p;
  };
  bf16_t* Wm0 = (bf16_t*)alloc((size_t)2496 * 320 * 2);   // 1.6 MB
  bf16_t* Wm1 = (bf16_t*)alloc((size_t)2496 * 832 * 2);   // 4.2 MB
  bf16_t* Wzf2 = (bf16_t*)alloc((size_t)1664 * 832 * 2);  // 2.8 MB
  bf16_t* A0 = (bf16_t*)alloc((size_t)32768 * 320 * 2);   // 21.0 MB
  bf16_t* H0buf[2], *H1buf[2];
  H0buf[0] = (bf16_t*)alloc((size_t)MC * LDH * 2);        // 13.6 MB each
  H0buf[1] = (bf16_t*)alloc((size_t)MC * LDH * 2);
  H1buf[0] = (bf16_t*)alloc((size_t)MC * LDH * 2);
  H1buf[1] = (bf16_t*)alloc((size_t)MC * LDH * 2);
  float* car0 = (float*)alloc((size_t)BATCH * HID * 4);   // 205 KB
  float* car1 = (float*)alloc((size_t)BATCH * HID * 4);
  float* car2 = (float*)alloc((size_t)BATCH * HID * 4);
  if (off > ws_size) return;  // ws too small: fail verification, don't fault

  // P0: weight transposes + bias rows (z=0..2) + A0 chunk-0 cast (z=3)
  prep_all<<<dim3(78, 26, 4), 256, 0, stream>>>(W0, W1, W2, b0, b1, b2, Wm0,
                                                Wm1, Wzf2, sent, A0);

  auto mkL0 = [&](int c) -> Role {
    return Role{A0 + (size_t)c * MC * 320, Wm0, H0buf[c & 1], car0,
                320, 0, 1, c == 0, c == NCHUNK - 1};
  };
  auto mkL1 = [&](int c) -> Role {
    return Role{H0buf[c & 1], Wm1, H1buf[c & 1], car1,
                832, 800, 1, c == 0, c == NCHUNK - 1};
  };
  auto mkL2 = [&](int c) -> Role {
    return Role{H1buf[c & 1], Wzf2, nullptr, car2,
                832, 1600, 2, c == 0, c == NCHUNK - 1};
  };
  auto mkCast = [&](int c) -> Role {
    return Role{(const bf16_t*)sent, nullptr, A0, nullptr, 0, c, 3, 0, 0};
  };

  // D0: L0(0) + cast chunks 1..3 (fill L0's idle tail with BW work)
  {
    Role a = mkL0(0), c1 = mkCast(1), c2 = mkCast(2), c3 = mkCast(3);
    gemm_scan_multi<<<dim3(13, 64, 4), 256, 0, stream>>>(a, c1, c2, c3, out);
  }
  // D1: L1(0) + L0(1)
  {
    Role a = mkL1(0), b_ = mkL0(1);
    gemm_scan_multi<<<dim3(13, 64, 2), 256, 0, stream>>>(a, b_, b_, b_, out);
  }
  // D2, D3: L1(c) + L2(c-1) + L0(c+1) for c = 1, 2
  for (int c = 1; c <= 2; ++c) {
    Role a = mkL1(c), b_ = mkL2(c - 1), d = mkL0(c + 1);
    gemm_scan_multi<<<dim3(13, 64, 3), 256, 0, stream>>>(a, b_, d, d, out);
  }
  // D4: L1(3) + L2(2)
  {
    Role a = mkL1(3), b_ = mkL2(2);
    gemm_scan_multi<<<dim3(13, 64, 2), 256, 0, stream>>>(a, b_, b_, b_, out);
  }
  // D5: final L2(3) on the 4-blocks/CU zf-only kernel (no tail)
  gemm_scan_c4<<<dim3(13, 64), 256, 0, stream>>>(H1buf[1], Wzf2, car2, out,
                                                 832, 1600, 0, 1);
}